// Round 12
// baseline (984.125 us; speedup 1.0000x reference)
//
#include <hip/hip_runtime.h>

#define DEVINL __device__ __forceinline__
#define AS __HIP_MEMORY_SCOPE_AGENT

constexpr int Bc = 32, Cc = 64, Tc = 1024, DIM2c = 128;
constexpr int Nn = Bc * Tc;            // 32768 nodes
constexpr int Ec = 524288;             // edges (self-loops handled in-kernel)
constexpr unsigned NBLK = 1024;        // persistent blocks (4/CU guaranteed)

typedef __bf16 bf16x8 __attribute__((ext_vector_type(8)));
typedef float  f32x4  __attribute__((ext_vector_type(4)));

// workspace layout (float offsets)
constexpr long O_RES   = 0;            // 4194304 fp32
constexpr long O_GOUT  = 4194304;      // 4194304 fp32
constexpr long O_XT    = 8388608;      // bf16 x 2097152: [b*1024+t][ci]
constexpr long O_HBF   = 9437184;      // bf16 x 2097152: flat bn0(x)
constexpr long O_XLQ   = 10485760;     // 2097152 uint (head-split bf16, u16[n][128])
constexpr long O_XRQ   = 12582912;     // 2097152 uint
constexpr long O_Z     = 16777216;     // 4194304 fp32
constexpr long O_WCBF  = 20971520;     // bf16 x 73728: [kk][co][ci]
constexpr long O_WLR   = 21008384;     // bf16 x 16384: [j 256][c 64]
constexpr long O_CHB   = 21016576;     // bf16 x 16384: [j 128][c 128]
constexpr long O_STAT  = 21024768;     // 1024 floats (zeroed; sums + barrier counters)
constexpr long O_CUR   = 21025792;     // 32768 ints (zeroed, contiguous w/ STAT)
constexpr long O_BUCK  = 21058560;     // 2097152 ints

DEVINL float unpack_lo(unsigned v) { return __uint_as_float(v << 16); }
DEVINL float unpack_hi(unsigned v) { return __uint_as_float(v & 0xffff0000u); }
DEVINL unsigned bfb(float f) { return (__float_as_uint(f) + 0x8000u) >> 16; }

// device-scope grid barrier: per-phase counter (memset-zeroed each call)
DEVINL void gbar(unsigned* cnt) {
    __syncthreads();
    if (threadIdx.x == 0) {
        __threadfence();                               // agent release (wb L2)
        __hip_atomic_fetch_add(cnt, 1u, __ATOMIC_RELEASE, AS);
        while (__hip_atomic_load(cnt, __ATOMIC_RELAXED, AS) < NBLK)
            __builtin_amdgcn_s_sleep(8);
        __threadfence();                               // agent acquire (inv L1/L2)
    }
    __syncthreads();
}

// ---------------- phase 1 units: weight prep / bn0 sums / bucket fill ----------------
DEVINL void setup_unit(int u, int tid, unsigned char* smem,
        const float* x, const float* cw, const float* wl, const float* wr,
        const float* chw, const int* ei,
        __bf16* wcbf, __bf16* wlrbf, __bf16* chwbf,
        float* sum0, float* sq0, int* cursor, int* bucket) {
    if (u < 416) {                             // weight prep (106496 items)
        int i = u * 256 + tid;
        if (i < 73728) {                       // wcbf[kk][co][ci] = cw[co][ci*9+kk]
            int kk = i >> 13, co = (i >> 6) & 127, ci = i & 63;
            wcbf[i] = (__bf16)cw[co * 576 + ci * 9 + kk];
        } else if (i < 73728 + 16384) {        // wlrbf[j][c]
            int j = i - 73728;
            int r = j >> 6, c = j & 63;
            float v = (r < 128) ? wl[r * 64 + c] : wr[(r - 128) * 64 + c];
            wlrbf[j] = (__bf16)v;
        } else {                               // chwbf[j][c]
            int j = i - 73728 - 16384;
            chwbf[j] = (__bf16)chw[j];
        }
    } else if (u < 672) {                      // bn0 sums (atomics into zeroed stat)
        float* ls = (float*)smem; float* lq = ls + 4;
        int pq = u - 416;
        int c = pq & 63, q = pq >> 6;
        const float4* base = (const float4*)(x + (long)q * 8 * 65536 + (long)c * 1024);
        float s = 0.f, qq = 0.f;
        for (int i = tid; i < 2048; i += 256) {
            int b = i >> 8, t4 = i & 255;
            float4 v = base[b * 16384 + t4];
            s += v.x + v.y + v.z + v.w;
            qq = fmaf(v.x, v.x, qq); qq = fmaf(v.y, v.y, qq);
            qq = fmaf(v.z, v.z, qq); qq = fmaf(v.w, v.w, qq);
        }
        for (int off = 32; off; off >>= 1) { s += __shfl_down(s, off); qq += __shfl_down(qq, off); }
        int w = tid >> 6, lane = tid & 63;
        if (lane == 0) { ls[w] = s; lq[w] = qq; }
        __syncthreads();
        if (tid == 0) {
            unsafeAtomicAdd(sum0 + c, ls[0] + ls[1] + ls[2] + ls[3]);
            unsafeAtomicAdd(sq0 + c, lq[0] + lq[1] + lq[2] + lq[3]);
        }
        __syncthreads();                       // protect ls/lq before next unit
    } else {                                   // bucket CSR fill (2048 units)
        int e = (u - 672) * 256 + tid;
        int t = ei[Ec + e];
        int slot = atomicAdd(cursor + t, 1);
        bucket[t * 64 + slot] = ei[e];
    }
}

// ---------------- phase 2 unit: bn0-apply -> hbf + xt ----------------
DEVINL void xprep_unit(int u, int tid, unsigned char* smem,
        const float* x, const float* sum0, const float* sq0,
        const float* g0, const float* b0, __bf16* hbf, __bf16* xt) {
    float (*lds)[65] = (float(*)[65])smem;
    float* scs = (float*)(smem + 16640);
    float* shs = scs + 64;
    if (tid < 64) {
        float mu = sum0[tid] * (1.f / 32768.f);
        float var = sq0[tid] * (1.f / 32768.f) - mu * mu;
        float rs = rsqrtf(var + 1e-5f);
        float sc = rs * g0[tid];
        scs[tid] = sc; shs[tid] = b0[tid] - mu * sc;
    }
    __syncthreads();
    int t0 = (u & 15) * 64;
    int b  = u >> 4;
    const float* xb = x + (long)b * 65536;
    for (int i = tid; i < 4096; i += 256) {
        int ci = i >> 6, tl = i & 63;
        float v = fmaf(xb[ci * 1024 + t0 + tl], scs[ci], shs[ci]);
        hbf[(long)b * 65536 + ci * 1024 + t0 + tl] = (__bf16)v;
        lds[ci][tl] = v;
    }
    __syncthreads();
    for (int i = tid; i < 4096; i += 256) {
        int t = i >> 6, ci = i & 63;
        xt[((long)b * 1024 + t0 + t) * 64 + ci] = (__bf16)lds[ci][t];
    }
}

// ---------------- phase 3 units: conv (LDS-staged) / gemm1 ----------------
constexpr int XS_STRIDE = 72;          // bf16 units; 144B rows, 16B aligned

DEVINL void conv_unit(int cid, int tid, unsigned char* smem,
        const __bf16* xt, const __bf16* wcbf, const float* cb, float* res) {
    __bf16* xs = (__bf16*)smem;
    int tbase = (cid & 7) * 128;
    int cohalf = (cid >> 3) & 1;
    int b = cid >> 4;
    const uint2* xg = (const uint2*)(xt + (long)b * 65536);
    for (int i = tid; i < 136 * 16; i += 256) {
        int row = i >> 4, c4 = i & 15;
        int t = tbase + row - 4;
        uint2 v; v.x = 0u; v.y = 0u;
        if ((unsigned)t < 1024u) v = xg[t * 16 + c4];
        *(uint2*)(xs + row * XS_STRIDE + c4 * 4) = v;
    }
    __syncthreads();
    int wv = tid >> 6, lane = tid & 63;
    int col = lane & 15, q = lane >> 4;
    int co0 = cohalf * 64 + wv * 16;
    bf16x8 af[18];
    #pragma unroll
    for (int kk = 0; kk < 9; kk++)
        #pragma unroll
        for (int ks = 0; ks < 2; ks++)
            af[kk * 2 + ks] = *(const bf16x8*)(wcbf +
                ((long)kk * 8192 + (long)(co0 + col) * 64 + ks * 32 + q * 8));
    float bi0 = cb[co0 + q * 4], bi1 = cb[co0 + q * 4 + 1];
    float bi2 = cb[co0 + q * 4 + 2], bi3 = cb[co0 + q * 4 + 3];
    for (int nt = 0; nt < 8; nt++) {
        int t0 = tbase + nt * 16;
        f32x4 acc; acc[0] = bi0; acc[1] = bi1; acc[2] = bi2; acc[3] = bi3;
        #pragma unroll
        for (int kk = 0; kk < 9; kk++) {
            const __bf16* rp = xs + (nt * 16 + col + kk) * XS_STRIDE + q * 8;
            #pragma unroll
            for (int ks = 0; ks < 2; ks++) {
                bf16x8 bfx = *(const bf16x8*)(rp + ks * 32);   // 16B aligned (stride 72)
                acc = __builtin_amdgcn_mfma_f32_16x16x32_bf16(af[kk * 2 + ks], bfx, acc, 0, 0, 0);
            }
        }
        long ob = (long)b * 131072 + (long)(co0 + q * 4) * 1024 + t0 + col;
        res[ob]        = fmaxf(acc[0], 0.f);
        res[ob + 1024] = fmaxf(acc[1], 0.f);
        res[ob + 2048] = fmaxf(acc[2], 0.f);
        res[ob + 3072] = fmaxf(acc[3], 0.f);
    }
    __syncthreads();                           // xs dead before next phase reuse
}

DEVINL void gemm1_unit(int mb, int tid, const __bf16* hbf, const __bf16* wlrbf,
        unsigned short* xl16, unsigned short* xr16) {
    int wv = tid >> 6, lane = tid & 63;
    int col = lane & 15, q = lane >> 4;
    int d0 = wv * 16;
    long mbase = (long)mb * 64;
    bf16x8 bfr[4][2];
    #pragma unroll
    for (int t = 0; t < 4; t++) {
        int j = d0 + t * 64 + col;
        #pragma unroll
        for (int ks = 0; ks < 2; ks++)
            bfr[t][ks] = *(const bf16x8*)(wlrbf + (long)j * 64 + ks * 32 + q * 8);
    }
    int d = d0 + col;
    for (int mt = 0; mt < 4; mt++) {
        long r0 = mbase + mt * 16;
        bf16x8 a0 = *(const bf16x8*)(hbf + (r0 + col) * 64 + q * 8);
        bf16x8 a1 = *(const bf16x8*)(hbf + (r0 + col) * 64 + 32 + q * 8);
        f32x4 acc[4];
        #pragma unroll
        for (int t = 0; t < 4; t++) { acc[t][0] = 0.f; acc[t][1] = 0.f; acc[t][2] = 0.f; acc[t][3] = 0.f; }
        #pragma unroll
        for (int t = 0; t < 4; t++) {
            acc[t] = __builtin_amdgcn_mfma_f32_16x16x32_bf16(a0, bfr[t][0], acc[t], 0, 0, 0);
            acc[t] = __builtin_amdgcn_mfma_f32_16x16x32_bf16(a1, bfr[t][1], acc[t], 0, 0, 0);
        }
        #pragma unroll
        for (int reg = 0; reg < 4; reg++) {
            long rb = (r0 + q * 4 + reg) * 128;
            xl16[rb + d]      = (unsigned short)bfb(acc[0][reg]);
            xl16[rb + 64 + d] = (unsigned short)bfb(acc[1][reg]);
            xr16[rb + d]      = (unsigned short)bfb(acc[2][reg]);
            xr16[rb + 64 + d] = (unsigned short)bfb(acc[3][reg]);
        }
    }
}

// ---------------- phase 4 unit: fused GATv2 (8 lanes/edge, per-head softmax) ----------------
DEVINL void gat_unit(int u, int tid, const uint4* xlq4, const uint4* xrq4,
        const int* cursor, const int* bucket, const float* att, float* gout) {
    int wid = (u * 256 + tid) >> 6;
    int lane = tid & 63;
    int g = lane >> 3, j = lane & 7;
    float av[16];
    #pragma unroll
    for (int k = 0; k < 16; k++) av[k] = att[16 * j + k];
    uint4 r0v = xrq4[(long)wid * 16 + j * 2];
    uint4 r1v = xrq4[(long)wid * 16 + j * 2 + 1];
    float xr[16];
    {
        unsigned ru[8] = {r0v.x, r0v.y, r0v.z, r0v.w, r1v.x, r1v.y, r1v.z, r1v.w};
        #pragma unroll
        for (int k = 0; k < 8; k++) { xr[2*k] = unpack_lo(ru[k]); xr[2*k+1] = unpack_hi(ru[k]); }
    }
    int cnt = cursor[wid];
    int s_all = bucket[wid * 64 + lane];
    float acc[16];
    #pragma unroll
    for (int k = 0; k < 16; k++) acc[k] = 0.f;
    float den = 0.f;
    int nit = (cnt + 8) >> 3;
    int sp = __shfl(s_all, g);
    sp = (g < cnt) ? sp : wid;
    uint4 p0 = xlq4[(long)sp * 16 + j * 2];
    uint4 p1 = xlq4[(long)sp * 16 + j * 2 + 1];
    for (int it = 0; it < nit; it++) {
        uint4 c0 = p0, c1 = p1;
        int icur = it * 8 + g;
        int inext = icur + 8;
        if (it + 1 < nit) {
            int sn = __shfl(s_all, inext & 63);
            sn = (inext < cnt) ? sn : wid;
            p0 = xlq4[(long)sn * 16 + j * 2];
            p1 = xlq4[(long)sn * 16 + j * 2 + 1];
        }
        unsigned uu[8] = {c0.x, c0.y, c0.z, c0.w, c1.x, c1.y, c1.z, c1.w};
        float xl[16];
        float w = 0.f;
        #pragma unroll
        for (int k = 0; k < 8; k++) {
            float lo = unpack_lo(uu[k]), hi = unpack_hi(uu[k]);
            xl[2*k] = lo; xl[2*k+1] = hi;
            float s0 = lo + xr[2*k]; s0 = fmaxf(s0, 0.2f * s0);
            float s1 = hi + xr[2*k+1]; s1 = fmaxf(s1, 0.2f * s1);
            w = fmaf(s1, av[2*k+1], fmaf(s0, av[2*k], w));
        }
        w += __shfl_xor(w, 1); w += __shfl_xor(w, 2);   // per-head 4-lane sum
        float e2 = (icur <= cnt) ? __expf(w) : 0.f;
        den += e2;
        #pragma unroll
        for (int k = 0; k < 16; k++) acc[k] = fmaf(e2, xl[k], acc[k]);
    }
    #pragma unroll
    for (int m = 8; m <= 32; m <<= 1) {
        den += __shfl_xor(den, m);
        #pragma unroll
        for (int k = 0; k < 16; k++) acc[k] += __shfl_xor(acc[k], m);
    }
    float rn = __builtin_amdgcn_rcpf(den);
    if (g == 0) {
        #pragma unroll
        for (int c = 0; c < 4; c++) {
            float4 o;
            o.x = acc[4*c] * rn;     o.y = acc[4*c+1] * rn;
            o.z = acc[4*c+2] * rn;   o.w = acc[4*c+3] * rn;
            *(float4*)(gout + (long)wid * 128 + 16 * j + 4 * c) = o;
        }
    }
}

// ---------------- phase 5 unit: bn stats over [N,128] ----------------
DEVINL void bn_stats_unit(int u, int tid, unsigned char* smem,
        const float* X, float* sum, float* sq) {
    float* ls = (float*)smem; float* lq = ls + 256;
    int f = tid & 127, sub = tid >> 7;
    int r0 = u * 256;
    float s = 0.f, q = 0.f;
    for (int r = r0 + sub; r < r0 + 256; r += 2) {
        float v = X[(long)r * 128 + f];
        s += v; q = fmaf(v, v, q);
    }
    ls[tid] = s; lq[tid] = q;
    __syncthreads();
    if (tid < 128) {
        s = ls[tid] + ls[tid + 128];
        q = lq[tid] + lq[tid + 128];
        unsafeAtomicAdd(sum + f, s);
        unsafeAtomicAdd(sq + f, q);
    }
    __syncthreads();
}

// ---------------- phase 6 unit: cheb_fused ----------------
DEVINL void cheb_unit(int u, int tid, unsigned char* smem,
        const float* gout, const float* res, const float* sum1, const float* sq1,
        const float* g1, const float* b1, const __bf16* chwbf,
        float* z, float* sum2, float* sq2) {
    unsigned* xs = (unsigned*)smem;            // 64x68 uints = 17408B
    float* scs = (float*)(smem + 17408);
    float* shs = scs + 128; float* cs = scs + 256; float* cq = scs + 384;
    if (tid < 128) {
        float mu = sum1[tid] * (1.f / 32768.f);
        float var = sq1[tid] * (1.f / 32768.f) - mu * mu;
        float rs = rsqrtf(var + 1e-5f);
        float sc = rs * g1[tid];
        scs[tid] = sc; shs[tid] = b1[tid] - mu * sc;
        cs[tid] = 0.f;
    } else cq[tid - 128] = 0.f;
    __syncthreads();
    long r0 = (long)u * 64;
    for (int i = tid; i < 2048; i += 256) {
        int row = i >> 5, c4 = i & 31;
        long gidx = (r0 + row) * 32 + c4;
        float4 v = ((const float4*)gout)[gidx];
        float4 r = ((const float4*)res)[gidx];
        int f0 = c4 * 4;
        float o0 = r.x + fmaxf(fmaf(v.x, scs[f0],     shs[f0]),     0.f);
        float o1 = r.y + fmaxf(fmaf(v.y, scs[f0 + 1], shs[f0 + 1]), 0.f);
        float o2 = r.z + fmaxf(fmaf(v.z, scs[f0 + 2], shs[f0 + 2]), 0.f);
        float o3 = r.w + fmaxf(fmaf(v.w, scs[f0 + 3], shs[f0 + 3]), 0.f);
        xs[row * 68 + c4 * 2]     = (bfb(o1) << 16) | bfb(o0);
        xs[row * 68 + c4 * 2 + 1] = (bfb(o3) << 16) | bfb(o2);
    }
    __syncthreads();
    int wv = tid >> 6, lane = tid & 63;
    int col = lane & 15, q = lane >> 4;
    bf16x8 bfr[2][4];
    #pragma unroll
    for (int t = 0; t < 2; t++) {
        int jj = wv * 16 + t * 64 + col;
        #pragma unroll
        for (int ks = 0; ks < 4; ks++)
            bfr[t][ks] = *(const bf16x8*)(chwbf + (long)jj * 128 + ks * 32 + q * 8);
    }
    float ls0 = 0.f, ls1 = 0.f, lq0 = 0.f, lq1 = 0.f;
    for (int mt = 0; mt < 4; mt++) {
        const __bf16* ap = (const __bf16*)xs + (mt * 16 + col) * 136;
        bf16x8 a[4];
        #pragma unroll
        for (int ks = 0; ks < 4; ks++)
            a[ks] = *(const bf16x8*)(ap + ks * 32 + q * 8);
        f32x4 acc[2];
        #pragma unroll
        for (int t = 0; t < 2; t++) { acc[t][0] = 0.f; acc[t][1] = 0.f; acc[t][2] = 0.f; acc[t][3] = 0.f; }
        #pragma unroll
        for (int t = 0; t < 2; t++)
            #pragma unroll
            for (int ks = 0; ks < 4; ks++)
                acc[t] = __builtin_amdgcn_mfma_f32_16x16x32_bf16(a[ks], bfr[t][ks], acc[t], 0, 0, 0);
        #pragma unroll
        for (int reg = 0; reg < 4; reg++) {
            float v0 = acc[0][reg], v1 = acc[1][reg];
            long zr = (r0 + mt * 16 + q * 4 + reg) * 128;
            z[zr + wv * 16 + col]      = v0;
            z[zr + wv * 16 + 64 + col] = v1;
            ls0 += v0; lq0 = fmaf(v0, v0, lq0);
            ls1 += v1; lq1 = fmaf(v1, v1, lq1);
        }
    }
    int j0 = wv * 16 + col;
    atomicAdd(&cs[j0], ls0);      atomicAdd(&cs[j0 + 64], ls1);
    atomicAdd(&cq[j0], lq0);      atomicAdd(&cq[j0 + 64], lq1);
    __syncthreads();
    if (tid < 128) unsafeAtomicAdd(sum2 + tid, cs[tid]);
    else unsafeAtomicAdd(sq2 + tid - 128, cq[tid - 128]);
    __syncthreads();
}

// ---------------- phase 7 unit: res + relu(bn(z)) -> out ----------------
DEVINL void bn_res_unit(int u, int tid, unsigned char* smem,
        const float* X, const float* res, const float* sum, const float* sq,
        const float* g, const float* bta, float* out) {
    float* scs = (float*)smem; float* shs = scs + 128;
    if (tid < 128) {
        float mu = sum[tid] * (1.f / 32768.f);
        float var = sq[tid] * (1.f / 32768.f) - mu * mu;
        float rs = rsqrtf(var + 1e-5f);
        float sc = rs * g[tid];
        scs[tid] = sc; shs[tid] = bta[tid] - mu * sc;
    }
    __syncthreads();
    int idx = u * 256 + tid;
    int f0 = (idx & 31) * 4;
    float4 v = ((const float4*)X)[idx];
    float4 r = ((const float4*)res)[idx];
    float4 o;
    o.x = r.x + fmaxf(fmaf(v.x, scs[f0],     shs[f0]),     0.f);
    o.y = r.y + fmaxf(fmaf(v.y, scs[f0 + 1], shs[f0 + 1]), 0.f);
    o.z = r.z + fmaxf(fmaf(v.z, scs[f0 + 2], shs[f0 + 2]), 0.f);
    o.w = r.w + fmaxf(fmaf(v.w, scs[f0 + 3], shs[f0 + 3]), 0.f);
    ((float4*)out)[idx] = o;
    __syncthreads();                           // scs/shs stable across units (same values) — barrier for LDS reuse safety
}

// ================= the mega-kernel =================
__global__ __launch_bounds__(256, 4) void mega(const float* __restrict__ x,
        const int* __restrict__ ei, const float* __restrict__ g0,
        const float* __restrict__ b0, const float* __restrict__ cw,
        const float* __restrict__ cb, const float* __restrict__ wl,
        const float* __restrict__ wr, const float* __restrict__ att,
        const float* __restrict__ g1, const float* __restrict__ b1,
        const float* __restrict__ chw, float* __restrict__ out,
        float* __restrict__ ws) {
    __shared__ __align__(16) unsigned char smem[19712];
    float*    res   = ws + O_RES;
    float*    gout  = ws + O_GOUT;
    __bf16*   xt    = (__bf16*)(ws + O_XT);
    __bf16*   hbf   = (__bf16*)(ws + O_HBF);
    unsigned* xlq   = (unsigned*)(ws + O_XLQ);
    unsigned* xrq   = (unsigned*)(ws + O_XRQ);
    float*    z     = ws + O_Z;
    __bf16*   wcbf  = (__bf16*)(ws + O_WCBF);
    __bf16*   wlrbf = (__bf16*)(ws + O_WLR);
    __bf16*   chwbf = (__bf16*)(ws + O_CHB);
    float*    st    = ws + O_STAT;
    int*      cursor = (int*)(ws + O_CUR);
    int*      bucket = (int*)(ws + O_BUCK);
    float *sum0 = st,       *sq0 = st + 64;
    float *sum1 = st + 128, *sq1 = st + 256;
    float *sum2 = st + 384, *sq2 = st + 512;
    unsigned* ctr = (unsigned*)(st + 960);     // 8 barrier counters, memset-zeroed

    int bid = blockIdx.x, tid = threadIdx.x;

    // P1: weight prep U bn0 sums U bucket fill (2720 units)
    for (int u = bid; u < 2720; u += NBLK)
        setup_unit(u, tid, smem, x, cw, wl, wr, chw, ei,
                   wcbf, wlrbf, chwbf, sum0, sq0, cursor, bucket);
    gbar(ctr + 0);
    // P2: bn0-apply -> hbf + xt (512 units)
    if (bid < 512) xprep_unit(bid, tid, smem, x, sum0, sq0, g0, b0, hbf, xt);
    gbar(ctr + 1);
    // P3: conv (512) U gemm1 (512)
    if (bid < 512) conv_unit(bid, tid, smem, xt, wcbf, cb, res);
    else gemm1_unit(bid - 512, tid, hbf, wlrbf,
                    (unsigned short*)xlq, (unsigned short*)xrq);
    gbar(ctr + 2);
    // P4: fused GATv2 (8192 units)
    for (int u = bid; u < 8192; u += NBLK)
        gat_unit(u, tid, (const uint4*)xlq, (const uint4*)xrq,
                 cursor, bucket, att, gout);
    gbar(ctr + 3);
    // P5: bn1 stats (128 units)
    if (bid < 128) bn_stats_unit(bid, tid, smem, gout, sum1, sq1);
    gbar(ctr + 4);
    // P6: h2 in LDS -> cheb GEMM -> z + stats2 (512 units)
    if (bid < 512) cheb_unit(bid, tid, smem, gout, res, sum1, sq1, g1, b1,
                             chwbf, z, sum2, sq2);
    gbar(ctr + 5);
    // P7: res + relu(bn(z)) -> out (4096 units)
    for (int u = bid; u < 4096; u += NBLK)
        bn_res_unit(u, tid, smem, z, res, sum2, sq2, g1, b1, out);
}

extern "C" void kernel_launch(void* const* d_in, const int* in_sizes, int n_in,
                              void* d_out, int out_size, void* d_ws, size_t ws_size,
                              hipStream_t stream) {
    const float* x   = (const float*)d_in[0];
    const int*   ei  = (const int*)d_in[1];
    const float* g0  = (const float*)d_in[2];
    const float* b0  = (const float*)d_in[3];
    const float* cw  = (const float*)d_in[4];
    const float* cb  = (const float*)d_in[5];
    const float* wl  = (const float*)d_in[6];
    const float* wr  = (const float*)d_in[7];
    const float* att = (const float*)d_in[8];
    // d_in[9] = gat_bias: cancels exactly inside the following bn2d -> unused
    const float* g1  = (const float*)d_in[10];
    const float* b1  = (const float*)d_in[11];
    const float* chw = (const float*)d_in[12];
    // d_in[13] = cheb_b: cancels inside the following bn2d -> unused
    float* out = (float*)d_out;
    float* ws  = (float*)d_ws;

    // zero stat block (incl. barrier counters) + cursor — contiguous
    hipMemsetAsync(ws + O_STAT, 0, (size_t)(1024 + 32768) * 4, stream);

    mega<<<NBLK, 256, 0, stream>>>(x, ei, g0, b0, cw, cb, wl, wr, att,
                                   g1, b1, chw, out, ws);
}

// Round 13
// 220.967 us; speedup vs baseline: 4.4537x; 4.4537x over previous
//
#include <hip/hip_runtime.h>

#define DEVINL __device__ __forceinline__

constexpr int Bc = 32, Cc = 64, Tc = 1024, DIM2c = 128;
constexpr int Nn = Bc * Tc;            // 32768 nodes
constexpr int Ec = 524288;             // edges (self-loops handled in-kernel)

typedef __bf16 bf16x8 __attribute__((ext_vector_type(8)));
typedef float  f32x4  __attribute__((ext_vector_type(4)));

// workspace layout (float offsets)
constexpr long O_RES   = 0;            // 4194304 fp32
constexpr long O_GOUT  = 4194304;      // bf16 pairs: 2097152 uints used
constexpr long O_XT    = 8388608;      // bf16 x 2097152: [b*1024+t][ci]
constexpr long O_HBF   = 9437184;      // bf16 x 2097152: flat bn0(x)
constexpr long O_XLQ   = 10485760;     // 2097152 uint (head-split bf16, u16[n][128])
constexpr long O_XRQ   = 12582912;     // 2097152 uint
constexpr long O_Z     = 16777216;     // bf16 pairs: 2097152 uints used
constexpr long O_WCBF  = 20971520;     // bf16 x 73728: [kk][co][ci]
constexpr long O_WLR   = 21008384;     // bf16 x 16384: [j 256][c 64]
constexpr long O_CHB   = 21016576;     // bf16 x 16384: [j 128][c 128]
constexpr long O_STAT  = 21024768;     // 1024 (zeroed by memset)
constexpr long O_CUR   = 21025792;     // 32768 ints (zeroed, contiguous w/ STAT)
constexpr long O_BUCK  = 21058560;     // 2097152 ints

DEVINL float unpack_lo(unsigned v) { return __uint_as_float(v << 16); }
DEVINL float unpack_hi(unsigned v) { return __uint_as_float(v & 0xffff0000u); }
DEVINL unsigned bfb(float f) { return (__float_as_uint(f) + 0x8000u) >> 16; }
DEVINL unsigned pk2(float lo, float hi) {
    return ((__float_as_uint(hi) + 0x8000u) & 0xffff0000u) | bfb(lo);
}

// ================= setup = prep_w U bn0_sums U bucket_fill =================
__global__ __launch_bounds__(256) void setup(const float* __restrict__ x,
        const float* __restrict__ cw, const float* __restrict__ wl,
        const float* __restrict__ wr, const float* __restrict__ chw,
        const int* __restrict__ ei,
        __bf16* __restrict__ wcbf, __bf16* __restrict__ wlrbf,
        __bf16* __restrict__ chwbf,
        float* __restrict__ sum0, float* __restrict__ sq0,
        int* __restrict__ cursor, int* __restrict__ bucket) {
    int bid = blockIdx.x, tid = threadIdx.x;
    if (bid < 416) {                           // weight prep (106496 items exactly)
        int i = bid * 256 + tid;
        if (i < 73728) {                       // wcbf[kk][co][ci] = cw[co][ci*9+kk]
            int kk = i >> 13, co = (i >> 6) & 127, ci = i & 63;
            wcbf[i] = (__bf16)cw[co * 576 + ci * 9 + kk];
        } else if (i < 73728 + 16384) {        // wlrbf[j][c]
            int j = i - 73728;
            int r = j >> 6, c = j & 63;
            float v = (r < 128) ? wl[r * 64 + c] : wr[(r - 128) * 64 + c];
            wlrbf[j] = (__bf16)v;
        } else {                               // chwbf[j][c]
            int j = i - 73728 - 16384;
            chwbf[j] = (__bf16)chw[j];
        }
    } else if (bid < 672) {                    // bn0 sums (atomics into memset-zeroed stat)
        int pq = bid - 416;
        int c = pq & 63, q = pq >> 6;
        const float4* base = (const float4*)(x + (long)q * 8 * 65536 + (long)c * 1024);
        float s = 0.f, qq = 0.f;
        for (int i = tid; i < 2048; i += 256) {
            int b = i >> 8, t4 = i & 255;
            float4 v = base[b * 16384 + t4];
            s += v.x + v.y + v.z + v.w;
            qq = fmaf(v.x, v.x, qq); qq = fmaf(v.y, v.y, qq);
            qq = fmaf(v.z, v.z, qq); qq = fmaf(v.w, v.w, qq);
        }
        for (int off = 32; off; off >>= 1) { s += __shfl_down(s, off); qq += __shfl_down(qq, off); }
        __shared__ float ls[4], lq[4];
        int w = tid >> 6, lane = tid & 63;
        if (lane == 0) { ls[w] = s; lq[w] = qq; }
        __syncthreads();
        if (tid == 0) {
            unsafeAtomicAdd(sum0 + c, ls[0] + ls[1] + ls[2] + ls[3]);
            unsafeAtomicAdd(sq0 + c, lq[0] + lq[1] + lq[2] + lq[3]);
        }
    } else {                                   // bucket CSR fill (2048 blocks)
        int e = (bid - 672) * 256 + tid;
        int t = ei[Ec + e];
        int slot = atomicAdd(cursor + t, 1);
        bucket[t * 64 + slot] = ei[e];
    }
}

// ================= xprep: bn0-apply -> hbf + xt =================
__global__ __launch_bounds__(256) void xprep(const float* __restrict__ x,
        const float* __restrict__ sum0, const float* __restrict__ sq0,
        const float* __restrict__ g0, const float* __restrict__ b0,
        __bf16* __restrict__ hbf, __bf16* __restrict__ xt) {
    __shared__ float lds[64][65];
    __shared__ float scs[64], shs[64];
    int tid = threadIdx.x;
    if (tid < 64) {
        float mu = sum0[tid] * (1.f / 32768.f);
        float var = sq0[tid] * (1.f / 32768.f) - mu * mu;
        float rs = rsqrtf(var + 1e-5f);
        float sc = rs * g0[tid];
        scs[tid] = sc; shs[tid] = b0[tid] - mu * sc;
    }
    __syncthreads();
    int t0 = blockIdx.x * 64;
    int b  = blockIdx.y;
    const float* xb = x + (long)b * 65536;
    for (int i = tid; i < 4096; i += 256) {
        int ci = i >> 6, tl = i & 63;
        float v = fmaf(xb[ci * 1024 + t0 + tl], scs[ci], shs[ci]);
        hbf[(long)b * 65536 + ci * 1024 + t0 + tl] = (__bf16)v;
        lds[ci][tl] = v;
    }
    __syncthreads();
    for (int i = tid; i < 4096; i += 256) {
        int t = i >> 6, ci = i & 63;
        xt[((long)b * 1024 + t0 + t) * 64 + ci] = (__bf16)lds[ci][t];
    }
}

// ================= conv (LDS-staged) U gemm1 (MFMA), interleaved roles =================
constexpr int XS_STRIDE = 72;          // bf16 units; 144B rows, 16B-aligned b128 frags

DEVINL void conv_role(int cid, const __bf16* __restrict__ xt,
        const __bf16* __restrict__ wcbf, const float* __restrict__ cb,
        float* __restrict__ res, __bf16* xs) {
    int tid = threadIdx.x;
    int tbase = (cid & 7) * 128;
    int cohalf = (cid >> 3) & 1;
    int b = cid >> 4;
    const uint2* xg = (const uint2*)(xt + (long)b * 65536);
    for (int i = tid; i < 136 * 16; i += 256) {
        int row = i >> 4, c4 = i & 15;
        int t = tbase + row - 4;
        uint2 v; v.x = 0u; v.y = 0u;
        if ((unsigned)t < 1024u) v = xg[t * 16 + c4];
        *(uint2*)(xs + row * XS_STRIDE + c4 * 4) = v;
    }
    __syncthreads();
    int wv = tid >> 6, lane = tid & 63;
    int col = lane & 15, q = lane >> 4;
    int co0 = cohalf * 64 + wv * 16;
    bf16x8 af[18];
    #pragma unroll
    for (int kk = 0; kk < 9; kk++)
        #pragma unroll
        for (int ks = 0; ks < 2; ks++)
            af[kk * 2 + ks] = *(const bf16x8*)(wcbf +
                ((long)kk * 8192 + (long)(co0 + col) * 64 + ks * 32 + q * 8));
    float bi0 = cb[co0 + q * 4], bi1 = cb[co0 + q * 4 + 1];
    float bi2 = cb[co0 + q * 4 + 2], bi3 = cb[co0 + q * 4 + 3];
    for (int nt = 0; nt < 8; nt++) {
        int t0 = tbase + nt * 16;
        f32x4 acc; acc[0] = bi0; acc[1] = bi1; acc[2] = bi2; acc[3] = bi3;
        #pragma unroll
        for (int kk = 0; kk < 9; kk++) {
            const __bf16* rp = xs + (nt * 16 + col + kk) * XS_STRIDE + q * 8;
            #pragma unroll
            for (int ks = 0; ks < 2; ks++) {
                bf16x8 bfx = *(const bf16x8*)(rp + ks * 32);   // 16B-aligned b128
                acc = __builtin_amdgcn_mfma_f32_16x16x32_bf16(af[kk * 2 + ks], bfx, acc, 0, 0, 0);
            }
        }
        long ob = (long)b * 131072 + (long)(co0 + q * 4) * 1024 + t0 + col;
        res[ob]        = fmaxf(acc[0], 0.f);
        res[ob + 1024] = fmaxf(acc[1], 0.f);
        res[ob + 2048] = fmaxf(acc[2], 0.f);
        res[ob + 3072] = fmaxf(acc[3], 0.f);
    }
}

// u16 slot d (d<64) = head0 dim d; slot 64+d = head1 dim d  (per node row of 128 u16)
DEVINL void gemm1_role(int mb, const __bf16* __restrict__ hbf,
        const __bf16* __restrict__ wlrbf,
        unsigned short* __restrict__ xl16, unsigned short* __restrict__ xr16) {
    int wv = threadIdx.x >> 6, lane = threadIdx.x & 63;
    int col = lane & 15, q = lane >> 4;
    int d0 = wv * 16;
    long mbase = (long)mb * 64;
    bf16x8 bfr[4][2];
    #pragma unroll
    for (int t = 0; t < 4; t++) {
        int j = d0 + t * 64 + col;
        #pragma unroll
        for (int ks = 0; ks < 2; ks++)
            bfr[t][ks] = *(const bf16x8*)(wlrbf + (long)j * 64 + ks * 32 + q * 8);
    }
    int d = d0 + col;
    for (int mt = 0; mt < 4; mt++) {
        long r0 = mbase + mt * 16;
        bf16x8 a0 = *(const bf16x8*)(hbf + (r0 + col) * 64 + q * 8);
        bf16x8 a1 = *(const bf16x8*)(hbf + (r0 + col) * 64 + 32 + q * 8);
        f32x4 acc[4];
        #pragma unroll
        for (int t = 0; t < 4; t++) { acc[t][0] = 0.f; acc[t][1] = 0.f; acc[t][2] = 0.f; acc[t][3] = 0.f; }
        #pragma unroll
        for (int t = 0; t < 4; t++) {
            acc[t] = __builtin_amdgcn_mfma_f32_16x16x32_bf16(a0, bfr[t][0], acc[t], 0, 0, 0);
            acc[t] = __builtin_amdgcn_mfma_f32_16x16x32_bf16(a1, bfr[t][1], acc[t], 0, 0, 0);
        }
        #pragma unroll
        for (int reg = 0; reg < 4; reg++) {
            long rb = (r0 + q * 4 + reg) * 128;
            xl16[rb + d]      = (unsigned short)bfb(acc[0][reg]);
            xl16[rb + 64 + d] = (unsigned short)bfb(acc[1][reg]);
            xr16[rb + d]      = (unsigned short)bfb(acc[2][reg]);
            xr16[rb + 64 + d] = (unsigned short)bfb(acc[3][reg]);
        }
    }
}

__global__ __launch_bounds__(256) void conv_gemm1(const __bf16* __restrict__ xt,
        const __bf16* __restrict__ wcbf, const float* __restrict__ cb,
        float* __restrict__ res, const __bf16* __restrict__ hbf,
        const __bf16* __restrict__ wlrbf,
        unsigned* __restrict__ xlq, unsigned* __restrict__ xrq) {
    __shared__ __align__(16) __bf16 xs[136 * XS_STRIDE];
    int bid = blockIdx.x;
    if (bid & 1) gemm1_role(bid >> 1, hbf, wlrbf, (unsigned short*)xlq, (unsigned short*)xrq);
    else conv_role(bid >> 1, xt, wcbf, cb, res, xs);
}

// ================= fused GATv2: 8 lanes/edge, per-head softmax; bf16 gout =================
__global__ __launch_bounds__(256) void gat_agg(const uint4* __restrict__ xlq4,
        const uint4* __restrict__ xrq4,
        const int* __restrict__ cursor, const int* __restrict__ bucket,
        const float* __restrict__ att, unsigned* __restrict__ goutb) {
    int wid = (blockIdx.x * 256 + threadIdx.x) >> 6;
    int lane = threadIdx.x & 63;
    int g = lane >> 3, j = lane & 7;
    float av[16];
    #pragma unroll
    for (int k = 0; k < 16; k++) av[k] = att[16 * j + k];
    uint4 r0v = xrq4[(long)wid * 16 + j * 2];
    uint4 r1v = xrq4[(long)wid * 16 + j * 2 + 1];
    float xr[16];
    {
        unsigned ru[8] = {r0v.x, r0v.y, r0v.z, r0v.w, r1v.x, r1v.y, r1v.z, r1v.w};
        #pragma unroll
        for (int k = 0; k < 8; k++) { xr[2*k] = unpack_lo(ru[k]); xr[2*k+1] = unpack_hi(ru[k]); }
    }
    int cnt = cursor[wid];
    int s_all = bucket[wid * 64 + lane];
    float acc[16];
    #pragma unroll
    for (int k = 0; k < 16; k++) acc[k] = 0.f;
    float den = 0.f;
    int nit = (cnt + 8) >> 3;
    int sp = __shfl(s_all, g);
    sp = (g < cnt) ? sp : wid;
    uint4 p0 = xlq4[(long)sp * 16 + j * 2];
    uint4 p1 = xlq4[(long)sp * 16 + j * 2 + 1];
    for (int it = 0; it < nit; it++) {
        uint4 c0 = p0, c1 = p1;
        int icur = it * 8 + g;
        int inext = icur + 8;
        if (it + 1 < nit) {
            int sn = __shfl(s_all, inext & 63);
            sn = (inext < cnt) ? sn : wid;
            p0 = xlq4[(long)sn * 16 + j * 2];
            p1 = xlq4[(long)sn * 16 + j * 2 + 1];
        }
        unsigned uu[8] = {c0.x, c0.y, c0.z, c0.w, c1.x, c1.y, c1.z, c1.w};
        float xl[16];
        float w = 0.f;
        #pragma unroll
        for (int k = 0; k < 8; k++) {
            float lo = unpack_lo(uu[k]), hi = unpack_hi(uu[k]);
            xl[2*k] = lo; xl[2*k+1] = hi;
            float s0 = lo + xr[2*k]; s0 = fmaxf(s0, 0.2f * s0);
            float s1 = hi + xr[2*k+1]; s1 = fmaxf(s1, 0.2f * s1);
            w = fmaf(s1, av[2*k+1], fmaf(s0, av[2*k], w));
        }
        w += __shfl_xor(w, 1); w += __shfl_xor(w, 2);   // per-head 4-lane sum
        float e2 = (icur <= cnt) ? __expf(w) : 0.f;
        den += e2;
        #pragma unroll
        for (int k = 0; k < 16; k++) acc[k] = fmaf(e2, xl[k], acc[k]);
    }
    #pragma unroll
    for (int m = 8; m <= 32; m <<= 1) {
        den += __shfl_xor(den, m);
        #pragma unroll
        for (int k = 0; k < 16; k++) acc[k] += __shfl_xor(acc[k], m);
    }
    float rn = __builtin_amdgcn_rcpf(den);
    if (g == 0) {                              // lanes 0..7 write 32B each (bf16 pairs)
        #pragma unroll
        for (int c = 0; c < 2; c++) {
            uint4 o;
            o.x = pk2(acc[8*c]     * rn, acc[8*c + 1] * rn);
            o.y = pk2(acc[8*c + 2] * rn, acc[8*c + 3] * rn);
            o.z = pk2(acc[8*c + 4] * rn, acc[8*c + 5] * rn);
            o.w = pk2(acc[8*c + 6] * rn, acc[8*c + 7] * rn);
            *(uint4*)(goutb + (long)wid * 64 + 8 * j + 4 * c) = o;
        }
    }
}

// ================= bn stats over bf16-pair [N,64 uints] =================
__global__ __launch_bounds__(256) void bn_stats_bf(const unsigned* __restrict__ G,
        float* __restrict__ sum, float* __restrict__ sq) {
    int c = threadIdx.x & 63, sub = threadIdx.x >> 6;   // c: uint column (2 features)
    int r0 = blockIdx.x * 256;
    float sl = 0.f, sh = 0.f, ql = 0.f, qh = 0.f;
    for (int r = r0 + sub; r < r0 + 256; r += 4) {
        unsigned v = G[(long)r * 64 + c];
        float lo = unpack_lo(v), hi = unpack_hi(v);
        sl += lo; ql = fmaf(lo, lo, ql);
        sh += hi; qh = fmaf(hi, hi, qh);
    }
    __shared__ float A[256], B[256], C[256], D[256];
    A[threadIdx.x] = sl; B[threadIdx.x] = sh;
    C[threadIdx.x] = ql; D[threadIdx.x] = qh;
    __syncthreads();
    if (threadIdx.x < 64) {
        int t = threadIdx.x;
        float s_lo = A[t] + A[t + 64] + A[t + 128] + A[t + 192];
        float s_hi = B[t] + B[t + 64] + B[t + 128] + B[t + 192];
        float q_lo = C[t] + C[t + 64] + C[t + 128] + C[t + 192];
        float q_hi = D[t] + D[t + 64] + D[t + 128] + D[t + 192];
        unsafeAtomicAdd(sum + 2 * t,     s_lo);
        unsafeAtomicAdd(sum + 2 * t + 1, s_hi);
        unsafeAtomicAdd(sq  + 2 * t,     q_lo);
        unsafeAtomicAdd(sq  + 2 * t + 1, q_hi);
    }
}

// ================= cheb_fused: h2 in LDS, z = h2 @ chw^T (bf16 out), stats2 =================
__global__ __launch_bounds__(256) void cheb_fused(const unsigned* __restrict__ goutb,
        const float* __restrict__ res, const float* __restrict__ sum1,
        const float* __restrict__ sq1, const float* __restrict__ g1,
        const float* __restrict__ b1, const __bf16* __restrict__ chwbf,
        unsigned* __restrict__ zb, float* __restrict__ sum2, float* __restrict__ sq2) {
    __shared__ unsigned xs[64 * 68];           // h2 tile, bf16 pairs, stride 68 uints
    __shared__ float scs[128], shs[128], cs[128], cq[128];
    int tid = threadIdx.x;
    if (tid < 128) {
        float mu = sum1[tid] * (1.f / 32768.f);
        float var = sq1[tid] * (1.f / 32768.f) - mu * mu;
        float rs = rsqrtf(var + 1e-5f);
        float sc = rs * g1[tid];
        scs[tid] = sc; shs[tid] = b1[tid] - mu * sc;
        cs[tid] = 0.f;
    } else cq[tid - 128] = 0.f;
    __syncthreads();
    long r0 = (long)blockIdx.x * 64;
    for (int i = tid; i < 2048; i += 256) {    // 64 rows x 32 quad-feature chunks
        int row = i >> 5, c4 = i & 31;
        long gidx = (r0 + row) * 32 + c4;
        uint2 gv = ((const uint2*)goutb)[gidx];
        float4 r = ((const float4*)res)[gidx];
        int f0 = c4 * 4;
        float v0 = unpack_lo(gv.x), v1 = unpack_hi(gv.x);
        float v2 = unpack_lo(gv.y), v3 = unpack_hi(gv.y);
        float o0 = r.x + fmaxf(fmaf(v0, scs[f0],     shs[f0]),     0.f);
        float o1 = r.y + fmaxf(fmaf(v1, scs[f0 + 1], shs[f0 + 1]), 0.f);
        float o2 = r.z + fmaxf(fmaf(v2, scs[f0 + 2], shs[f0 + 2]), 0.f);
        float o3 = r.w + fmaxf(fmaf(v3, scs[f0 + 3], shs[f0 + 3]), 0.f);
        xs[row * 68 + c4 * 2]     = pk2(o0, o1);
        xs[row * 68 + c4 * 2 + 1] = pk2(o2, o3);
    }
    __syncthreads();
    int wv = tid >> 6, lane = tid & 63;
    int col = lane & 15, q = lane >> 4;
    bf16x8 bfr[2][4];
    #pragma unroll
    for (int t = 0; t < 2; t++) {
        int jj = wv * 16 + t * 64 + col;
        #pragma unroll
        for (int ks = 0; ks < 4; ks++)
            bfr[t][ks] = *(const bf16x8*)(chwbf + (long)jj * 128 + ks * 32 + q * 8);
    }
    float ls0 = 0.f, ls1 = 0.f, lq0 = 0.f, lq1 = 0.f;
    bool evenc = (col & 1) == 0;
    int fpair0 = (wv * 16 + col) >> 1;         // uint index within z row (first half)
    for (int mt = 0; mt < 4; mt++) {
        const __bf16* ap = (const __bf16*)xs + (mt * 16 + col) * 136;
        bf16x8 a[4];
        #pragma unroll
        for (int ks = 0; ks < 4; ks++)
            a[ks] = *(const bf16x8*)(ap + ks * 32 + q * 8);
        f32x4 acc[2];
        #pragma unroll
        for (int t = 0; t < 2; t++) { acc[t][0] = 0.f; acc[t][1] = 0.f; acc[t][2] = 0.f; acc[t][3] = 0.f; }
        #pragma unroll
        for (int t = 0; t < 2; t++)
            #pragma unroll
            for (int ks = 0; ks < 4; ks++)
                acc[t] = __builtin_amdgcn_mfma_f32_16x16x32_bf16(a[ks], bfr[t][ks], acc[t], 0, 0, 0);
        #pragma unroll
        for (int reg = 0; reg < 4; reg++) {
            float v0 = acc[0][reg], v1 = acc[1][reg];
            // stats from fp32 values (all lanes)
            ls0 += v0; lq0 = fmaf(v0, v0, lq0);
            ls1 += v1; lq1 = fmaf(v1, v1, lq1);
            // bf16-pair store: even col packs (own, col+1 partner)
            float n0 = __shfl_xor(v0, 1);
            float n1 = __shfl_xor(v1, 1);
            if (evenc) {
                long zrow = (r0 + mt * 16 + q * 4 + reg) * 64;
                zb[zrow + fpair0]      = pk2(v0, n0);
                zb[zrow + 32 + fpair0] = pk2(v1, n1);
            }
        }
    }
    int j0 = wv * 16 + col;
    atomicAdd(&cs[j0], ls0);      atomicAdd(&cs[j0 + 64], ls1);
    atomicAdd(&cq[j0], lq0);      atomicAdd(&cq[j0 + 64], lq1);
    __syncthreads();
    if (tid < 128) unsafeAtomicAdd(sum2 + tid, cs[tid]);
    else unsafeAtomicAdd(sq2 + tid - 128, cq[tid - 128]);
}

// ================= res + relu(bn(z bf16)) -> fp32 out =================
__global__ __launch_bounds__(256) void bn_res(const unsigned* __restrict__ zb,
        const float* __restrict__ res, const float* __restrict__ sum,
        const float* __restrict__ sq, const float* __restrict__ g,
        const float* __restrict__ bta, float* __restrict__ out) {
    __shared__ float scs[128], shs[128];
    int tid = threadIdx.x;
    if (tid < 128) {
        float mu = sum[tid] * (1.f / 32768.f);
        float var = sq[tid] * (1.f / 32768.f) - mu * mu;
        float rs = rsqrtf(var + 1e-5f);
        float sc = rs * g[tid];
        scs[tid] = sc; shs[tid] = bta[tid] - mu * sc;
    }
    __syncthreads();
    int idx = blockIdx.x * 256 + tid;
    int f0 = (idx & 31) * 4;
    uint2 zv = ((const uint2*)zb)[idx];
    float4 r = ((const float4*)res)[idx];
    float v0 = unpack_lo(zv.x), v1 = unpack_hi(zv.x);
    float v2 = unpack_lo(zv.y), v3 = unpack_hi(zv.y);
    float4 o;
    o.x = r.x + fmaxf(fmaf(v0, scs[f0],     shs[f0]),     0.f);
    o.y = r.y + fmaxf(fmaf(v1, scs[f0 + 1], shs[f0 + 1]), 0.f);
    o.z = r.z + fmaxf(fmaf(v2, scs[f0 + 2], shs[f0 + 2]), 0.f);
    o.w = r.w + fmaxf(fmaf(v3, scs[f0 + 3], shs[f0 + 3]), 0.f);
    ((float4*)out)[idx] = o;
}

extern "C" void kernel_launch(void* const* d_in, const int* in_sizes, int n_in,
                              void* d_out, int out_size, void* d_ws, size_t ws_size,
                              hipStream_t stream) {
    const float* x   = (const float*)d_in[0];
    const int*   ei  = (const int*)d_in[1];
    const float* g0  = (const float*)d_in[2];
    const float* b0  = (const float*)d_in[3];
    const float* cw  = (const float*)d_in[4];
    const float* cb  = (const float*)d_in[5];
    const float* wl  = (const float*)d_in[6];
    const float* wr  = (const float*)d_in[7];
    const float* att = (const float*)d_in[8];
    // d_in[9] = gat_bias: cancels exactly inside the following bn2d -> unused
    const float* g1  = (const float*)d_in[10];
    const float* b1  = (const float*)d_in[11];
    const float* chw = (const float*)d_in[12];
    // d_in[13] = cheb_b: cancels inside the following bn2d -> unused
    float* out = (float*)d_out;

    float* ws = (float*)d_ws;
    float*    res   = ws + O_RES;
    unsigned* goutb = (unsigned*)(ws + O_GOUT);
    __bf16*   xt    = (__bf16*)(ws + O_XT);
    __bf16*   hbf   = (__bf16*)(ws + O_HBF);
    unsigned* xlq   = (unsigned*)(ws + O_XLQ);
    unsigned* xrq   = (unsigned*)(ws + O_XRQ);
    unsigned* zb    = (unsigned*)(ws + O_Z);
    __bf16*   wcbf  = (__bf16*)(ws + O_WCBF);
    __bf16*   wlrbf = (__bf16*)(ws + O_WLR);
    __bf16*   chwbf = (__bf16*)(ws + O_CHB);
    float*    st    = ws + O_STAT;
    int*      cursor = (int*)(ws + O_CUR);
    int*      bucket = (int*)(ws + O_BUCK);
    float *sum0 = st,       *sq0 = st + 64;
    float *sum1 = st + 128, *sq1 = st + 256;
    float *sum2 = st + 384, *sq2 = st + 512;

    // one memset covers stat block (4KB) + cursor (128KB), contiguous
    hipMemsetAsync(st, 0, (size_t)(1024 + 32768) * 4, stream);

    // prep_w U bn0_sums U bucket_fill
    setup<<<2720, 256, 0, stream>>>(x, cw, wl, wr, chw, ei,
                                    wcbf, wlrbf, chwbf, sum0, sq0, cursor, bucket);
    // bn0-apply -> bf16 (flat + transposed)
    xprep<<<dim3(16, 32), 256, 0, stream>>>(x, sum0, sq0, g0, b0, hbf, xt);
    // conv1d+relu->res U gemm1->xlq/xrq (MFMA, interleaved roles, LDS-staged conv)
    conv_gemm1<<<1024, 256, 0, stream>>>(xt, wcbf, cb, res, hbf, wlrbf, xlq, xrq);
    // fused GATv2 (8 lanes/edge, per-head softmax) -> bf16 gout
    gat_agg<<<8192, 256, 0, stream>>>((const uint4*)xlq, (const uint4*)xrq,
                                      cursor, bucket, att, goutb);
    // bn1 stats (bf16 input)
    bn_stats_bf<<<128, 256, 0, stream>>>(goutb, sum1, sq1);
    // h2 in LDS -> cheb GEMM -> z (bf16) + stats2
    cheb_fused<<<512, 256, 0, stream>>>(goutb, res, sum1, sq1, g1, b1, chwbf,
                                        zb, sum2, sq2);
    // bn + relu + residual -> out
    bn_res<<<4096, 256, 0, stream>>>(zb, res, sum2, sq2, g1, b1, out);
}